// Round 8
// baseline (626.988 us; speedup 1.0000x reference)
//
#include <hip/hip_runtime.h>
#include <hip/hip_bf16.h>

typedef _Float16 f16x8 __attribute__((ext_vector_type(8)));
typedef float f32x4 __attribute__((ext_vector_type(4)));

#define BQ 65536            // B*Q = 8*8192
#define KPAD0 640           // W0t row stride; effective K = 608 (last 32 all-pad skipped)
#define HID 256
#define NOUT 27
#define ZOFF 1179648        // featT element count; featT+ZOFF == zbuf (zeros)

// ---------------- feat (B,C,H,W) f32 -> featT (B,H,W,C) f16 -----------------
__global__ __launch_bounds__(256) void feat_transpose(
    const float* __restrict__ feat, _Float16* __restrict__ featT,
    _Float16* __restrict__ zbuf)
{
    __shared__ float tile[64 * 49];
    int bh = blockIdx.x;                 // 0..383 = b*48+h
    int b = bh / 48, h = bh - b * 48;
    int t = threadIdx.x;
    if (bh == 0 && t < 128) zbuf[t] = (_Float16)0.f;
    #pragma unroll
    for (int i = 0; i < 12; i++) {
        int idx = t + i * 256;           // < 3072
        int c = idx / 48, w = idx - c * 48;
        tile[c * 49 + w] = feat[(((size_t)b * 64 + c) * 48 + h) * 48 + w];
    }
    __syncthreads();
    #pragma unroll
    for (int i = 0; i < 12; i++) {
        int idx = t + i * 256;
        int w = idx >> 6, c = idx & 63;
        featT[(((size_t)b * 48 + h) * 48 + w) * 64 + c] = (_Float16)tile[c * 49 + w];
    }
}

// ---------------- weight transpose+cast: wt[n*Kpad+k] = w[k*Nin+n] ----------
__global__ void transpose_cast(const float* __restrict__ w, _Float16* __restrict__ wt,
                               int Kin, int Nin, int Kpad, int Npad) {
    int idx = blockIdx.x * 256 + threadIdx.x;
    if (idx >= Npad * Kpad) return;
    int n = idx / Kpad, k = idx - n * Kpad;
    float v = (n < Nin && k < Kin) ? w[k * Nin + n] : 0.f;
    wt[idx] = (_Float16)v;
}

// w0 with K-permutation: kp<576 -> src_k = (kp&63)*9 + (kp>>6)  (pixel-major)
__global__ void transpose_cast_w0(const float* __restrict__ w0, _Float16* __restrict__ wt) {
    int idx = blockIdx.x * 256 + threadIdx.x;
    if (idx >= 256 * KPAD0) return;
    int n = idx / KPAD0, kp = idx - n * KPAD0;
    int src = (kp < 576) ? ((kp & 63) * 9 + (kp >> 6)) : kp;
    float v = (src < 596) ? w0[src * 256 + n] : 0.f;
    wt[idx] = (_Float16)v;
}

// ---------------- megakernel: one (64-row, shift) tile, 5 layers ------------
// grid = 4096: s = blk&3, bq0 = (blk>>2)*64. 256 thr = 4 waves (N-split).
// BARRIER-FREE K-loops: B-fragments load global->VGPR (L2-hot weights),
// L0 A-fragments load global->VGPR via pixA offset table. act in LDS is
// read without barriers (stable within a layer); barriers only bracket
// the in-place epilogues (~9 per block vs ~104 in the staged version).
__global__ __launch_bounds__(256, 2) void mega(
    const _Float16* __restrict__ featT, const float* __restrict__ coord,
    const float* __restrict__ cell,
    const _Float16* __restrict__ W0t, const _Float16* __restrict__ W1t,
    const _Float16* __restrict__ W2t, const _Float16* __restrict__ W3t,
    const _Float16* __restrict__ W4t,
    const float* __restrict__ b0, const float* __restrict__ b1,
    const float* __restrict__ b2, const float* __restrict__ b3,
    const float* __restrict__ b4, float* __restrict__ preds)
{
    __shared__ _Float16 act[64 * 256];   // 32 KB activation tile (swizzled)
    __shared__ int   pixA[9 * 64];       // per-(pixel,row) featT element offset
    __shared__ int   rc_s[64][2];
    __shared__ float q_s[64][2];
    __shared__ float wgt[64];

    int t = threadIdx.x;
    int wave = t >> 6, lane = t & 63;
    int lrow = lane & 15, lq = lane >> 4;
    int blk = blockIdx.x;
    int s = blk & 3;
    int bq0 = (blk >> 2) * 64;

    // ---- prologue A: this shift's rc/q + all-4 areas -> blend weight --------
    if (t < 64) {
        int bq = bq0 + t;
        const float* cp = coord + (size_t)bq * 18;
        float areas[4]; int mri = 0, mci = 0; float mqx = 0.f, mqy = 0.f;
        #pragma unroll
        for (int ss = 0; ss < 4; ss++) {
            float vx = (ss & 2) ? 1.f : -1.f, vy = (ss & 1) ? 1.f : -1.f;
            float cx = cp[8] + vx * (1.f / 48.f) + 1e-6f;
            float cy = cp[9] + vy * (1.f / 48.f) + 1e-6f;
            cx = fminf(fmaxf(cx, -1.f + 1e-6f), 1.f - 1e-6f);
            cy = fminf(fmaxf(cy, -1.f + 1e-6f), 1.f - 1e-6f);
            int ri = (int)rintf((cx + 1.f) * 24.f - 0.5f); ri = min(max(ri, 0), 47);
            int ci = (int)rintf((cy + 1.f) * 24.f - 0.5f); ci = min(max(ci, 0), 47);
            float qx = (float)(2 * ri + 1) / 48.f - 1.f;
            float qy = (float)(2 * ci + 1) / 48.f - 1.f;
            areas[ss] = fabsf((cp[0] - qx) * 2304.f * (cp[1] - qy)) + 1e-9f;
            if (ss == s) { mri = ri; mci = ci; mqx = qx; mqy = qy; }
        }
        float tot = areas[0] + areas[1] + areas[2] + areas[3];
        wgt[t] = areas[s ^ 3] / tot;
        rc_s[t][0] = mri; rc_s[t][1] = mci;
        q_s[t][0] = mqx;  q_s[t][1] = mqy;
    }
    __syncthreads();
    // ---- prologue B: pixel offset table (9 neighbors x 64 rows) -------------
    {
        int e = t;
        if (e < 576) {
            int p = e >> 6, row = e & 63;
            int di = p / 3 - 1, dj = p - (p / 3) * 3 - 1;
            int ri = rc_s[row][0] + di, ci = rc_s[row][1] + dj;
            int b = (bq0 + row) >> 13;
            pixA[e] = ((unsigned)ri < 48u && (unsigned)ci < 48u)
                    ? (((b * 48 + ri) * 48 + ci) << 6) : ZOFF;
        }
        e = t + 256;
        if (e < 576) {
            int p = e >> 6, row = e & 63;
            int di = p / 3 - 1, dj = p - (p / 3) * 3 - 1;
            int ri = rc_s[row][0] + di, ci = rc_s[row][1] + dj;
            int b = (bq0 + row) >> 13;
            pixA[e] = ((unsigned)ri < 48u && (unsigned)ci < 48u)
                    ? (((b * 48 + ri) * 48 + ci) << 6) : ZOFF;
        }
        e = t + 512;
        if (e < 576) {
            int p = e >> 6, row = e & 63;
            int di = p / 3 - 1, dj = p - (p / 3) * 3 - 1;
            int ri = rc_s[row][0] + di, ci = rc_s[row][1] + dj;
            int b = (bq0 + row) >> 13;
            pixA[e] = ((unsigned)ri < 48u && (unsigned)ci < 48u)
                    ? (((b * 48 + ri) * 48 + ci) << 6) : ZOFF;
        }
    }
    __syncthreads();

    f32x4 acc[4][4];
    #pragma unroll
    for (int mi = 0; mi < 4; mi++)
        #pragma unroll
        for (int ni = 0; ni < 4; ni++) acc[mi][ni] = (f32x4){0.f, 0.f, 0.f, 0.f};

    // ================= layer 0: barrier-free, operands from global ===========
    for (int p = 0; p < 9; p++) {
        #pragma unroll
        for (int half = 0; half < 2; half++) {
            f16x8 af[4], bf[4];
            #pragma unroll
            for (int mi = 0; mi < 4; mi++) {
                int off = pixA[p * 64 + mi * 16 + lrow];
                af[mi] = *(const f16x8*)(featT + off + half * 32 + lq * 8);
            }
            int k0 = p * 64 + half * 32;
            #pragma unroll
            for (int ni = 0; ni < 4; ni++) {
                int br = wave * 64 + ni * 16 + lrow;
                bf[ni] = *(const f16x8*)&W0t[(size_t)br * KPAD0 + k0 + lq * 8];
            }
            #pragma unroll
            for (int mi = 0; mi < 4; mi++)
                #pragma unroll
                for (int ni = 0; ni < 4; ni++)
                    acc[mi][ni] = __builtin_amdgcn_mfma_f32_16x16x32_f16(
                        af[mi], bf[ni], acc[mi][ni], 0, 0, 0);
        }
    }
    {   // rel/cell chunk (k = 576..607): A computed per-lane in registers
        f16x8 af[4], bf[4];
        #pragma unroll
        for (int mi = 0; mi < 4; mi++) {
            int row = mi * 16 + lrow;
            int bq = bq0 + row;
            const float* cp2 = coord + (size_t)bq * 18;
            float qx = q_s[row][0], qy = q_s[row][1];
            _Float16 tmp[8];
            #pragma unroll
            for (int j = 0; j < 8; j++) {
                int idx = lq * 8 + j;
                float v;
                if (idx < 18) v = (idx & 1) ? (cp2[idx] - qy) : ((cp2[idx] - qx) * 2304.f);
                else if (idx == 18) v = cell[(size_t)bq * 2] * 48.f;
                else if (idx == 19) v = cell[(size_t)bq * 2 + 1] * 48.f;
                else v = 0.f;
                tmp[j] = (_Float16)v;
            }
            af[mi] = *(f16x8*)tmp;
        }
        #pragma unroll
        for (int ni = 0; ni < 4; ni++) {
            int br = wave * 64 + ni * 16 + lrow;
            bf[ni] = *(const f16x8*)&W0t[(size_t)br * KPAD0 + 576 + lq * 8];
        }
        #pragma unroll
        for (int mi = 0; mi < 4; mi++)
            #pragma unroll
            for (int ni = 0; ni < 4; ni++)
                acc[mi][ni] = __builtin_amdgcn_mfma_f32_16x16x32_f16(
                    af[mi], bf[ni], acc[mi][ni], 0, 0, 0);
    }
    {   // act = relu(acc + b0)  (nothing read act yet; barrier after)
        float bvv[4];
        #pragma unroll
        for (int ni = 0; ni < 4; ni++) bvv[ni] = b0[wave * 64 + ni * 16 + lrow];
        #pragma unroll
        for (int mi = 0; mi < 4; mi++)
            #pragma unroll
            for (int ni = 0; ni < 4; ni++) {
                int cw = wave * 64 + ni * 16 + lrow;
                #pragma unroll
                for (int rr = 0; rr < 4; rr++) {
                    float v = acc[mi][ni][rr] + bvv[ni];
                    v = v > 0.f ? v : 0.f;
                    int rw = mi * 16 + lq * 4 + rr;
                    int gp = ((cw >> 3) ^ (rw & 31)) & 31;
                    act[rw * 256 + gp * 8 + (cw & 7)] = (_Float16)v;
                }
            }
    }
    __syncthreads();

    // ================= hidden layers 1..3: barrier-free K-loops ==============
    for (int layer = 0; layer < 3; layer++) {
        const _Float16* Wl = (layer == 0) ? W1t : (layer == 1) ? W2t : W3t;
        const float*    bl = (layer == 0) ? b1  : (layer == 1) ? b2  : b3;
        #pragma unroll
        for (int mi = 0; mi < 4; mi++)
            #pragma unroll
            for (int ni = 0; ni < 4; ni++) acc[mi][ni] = (f32x4){0.f, 0.f, 0.f, 0.f};
        #pragma unroll 2
        for (int k0 = 0; k0 < 256; k0 += 32) {
            f16x8 af[4], bf[4];
            #pragma unroll
            for (int mi = 0; mi < 4; mi++) {
                int ar = mi * 16 + lrow;
                int gp = (((k0 >> 3) + lq) ^ (ar & 31)) & 31;
                af[mi] = *(const f16x8*)&act[ar * 256 + gp * 8];
            }
            #pragma unroll
            for (int ni = 0; ni < 4; ni++) {
                int br = wave * 64 + ni * 16 + lrow;
                bf[ni] = *(const f16x8*)&Wl[(size_t)br * 256 + k0 + lq * 8];
            }
            #pragma unroll
            for (int mi = 0; mi < 4; mi++)
                #pragma unroll
                for (int ni = 0; ni < 4; ni++)
                    acc[mi][ni] = __builtin_amdgcn_mfma_f32_16x16x32_f16(
                        af[mi], bf[ni], acc[mi][ni], 0, 0, 0);
        }
        __syncthreads();   // all act reads done before in-place overwrite
        {
            float bvv[4];
            #pragma unroll
            for (int ni = 0; ni < 4; ni++) bvv[ni] = bl[wave * 64 + ni * 16 + lrow];
            #pragma unroll
            for (int mi = 0; mi < 4; mi++)
                #pragma unroll
                for (int ni = 0; ni < 4; ni++) {
                    int cw = wave * 64 + ni * 16 + lrow;
                    #pragma unroll
                    for (int rr = 0; rr < 4; rr++) {
                        float v = acc[mi][ni][rr] + bvv[ni];
                        v = v > 0.f ? v : 0.f;
                        int rw = mi * 16 + lq * 4 + rr;
                        int gp = ((cw >> 3) ^ (rw & 31)) & 31;
                        act[rw * 256 + gp * 8 + (cw & 7)] = (_Float16)v;
                    }
                }
        }
        __syncthreads();
    }

    // ================= final layer: M-split across waves (16 rows each) ======
    f32x4 acc2[2];
    acc2[0] = (f32x4){0.f, 0.f, 0.f, 0.f};
    acc2[1] = (f32x4){0.f, 0.f, 0.f, 0.f};
    int mrow0 = wave * 16;
    #pragma unroll 2
    for (int k0 = 0; k0 < 256; k0 += 32) {
        f16x8 af, bf[2];
        {
            int ar = mrow0 + lrow;
            int gp = (((k0 >> 3) + lq) ^ (ar & 31)) & 31;
            af = *(const f16x8*)&act[ar * 256 + gp * 8];
        }
        #pragma unroll
        for (int ni = 0; ni < 2; ni++) {
            int br = ni * 16 + lrow;
            bf[ni] = *(const f16x8*)&W4t[(size_t)br * 256 + k0 + lq * 8];
        }
        #pragma unroll
        for (int ni = 0; ni < 2; ni++)
            acc2[ni] = __builtin_amdgcn_mfma_f32_16x16x32_f16(af, bf[ni], acc2[ni], 0, 0, 0);
    }

    // weighted partial -> exclusive preds[s] slice (plain stores, no atomics)
    {
        float bv0 = b4[lrow];
        float bv1 = (lrow < 11) ? b4[16 + lrow] : 0.f;
        float* pr = preds + (size_t)s * (BQ * NOUT);
        #pragma unroll
        for (int rr = 0; rr < 4; rr++) {
            int row = mrow0 + lq * 4 + rr;
            float w = wgt[row];
            size_t obase = (size_t)(bq0 + row) * 27;
            pr[obase + lrow] = w * (acc2[0][rr] + bv0);
            if (lrow < 11)
                pr[obase + 16 + lrow] = w * (acc2[1][rr] + bv1);
        }
    }
}

// ---------------- combine: out = sum of 4 weighted partials ------------------
__global__ __launch_bounds__(256) void combine_kernel(
    const float* __restrict__ preds, float* __restrict__ out)
{
    int idx = blockIdx.x * 256 + threadIdx.x;
    if (idx >= BQ * NOUT) return;
    const size_t st = (size_t)BQ * NOUT;
    out[idx] = preds[idx] + preds[st + idx] + preds[2 * st + idx] + preds[3 * st + idx];
}

extern "C" void kernel_launch(void* const* d_in, const int* in_sizes, int n_in,
                              void* d_out, int out_size, void* d_ws, size_t ws_size,
                              hipStream_t stream) {
    const float* feat  = (const float*)d_in[0];
    const float* coord = (const float*)d_in[1];
    const float* cell  = (const float*)d_in[2];
    const float* w0 = (const float*)d_in[3];  const float* b0 = (const float*)d_in[4];
    const float* w1 = (const float*)d_in[5];  const float* b1 = (const float*)d_in[6];
    const float* w2 = (const float*)d_in[7];  const float* b2 = (const float*)d_in[8];
    const float* w3 = (const float*)d_in[9];  const float* b3 = (const float*)d_in[10];
    const float* w4 = (const float*)d_in[11]; const float* b4 = (const float*)d_in[12];
    float* out = (float*)d_out;

    char* ws = (char*)d_ws;
    size_t off = 0;
    _Float16* W0t = (_Float16*)(ws + off); off += (size_t)256 * KPAD0 * 2;
    _Float16* W1t = (_Float16*)(ws + off); off += (size_t)256 * 256 * 2;
    _Float16* W2t = (_Float16*)(ws + off); off += (size_t)256 * 256 * 2;
    _Float16* W3t = (_Float16*)(ws + off); off += (size_t)256 * 256 * 2;
    _Float16* W4t = (_Float16*)(ws + off); off += (size_t)32 * 256 * 2;
    _Float16* featT = (_Float16*)(ws + off); off += (size_t)ZOFF * 2;
    _Float16* zbuf  = (_Float16*)(ws + off); off += 512;   // featT + ZOFF == zbuf
    float* preds    = (float*)(ws + off);    off += (size_t)4 * BQ * NOUT * 4;

    feat_transpose<<<8 * 48, 256, 0, stream>>>(feat, featT, zbuf);
    transpose_cast_w0<<<(256 * KPAD0 + 255) / 256, 256, 0, stream>>>(w0, W0t);
    transpose_cast<<<256, 256, 0, stream>>>(w1, W1t, 256, 256, 256, 256);
    transpose_cast<<<256, 256, 0, stream>>>(w2, W2t, 256, 256, 256, 256);
    transpose_cast<<<256, 256, 0, stream>>>(w3, W3t, 256, 256, 256, 256);
    transpose_cast<<<32, 256, 0, stream>>>(w4, W4t, 256, NOUT, 256, 32);

    mega<<<4 * (BQ / 64), 256, 0, stream>>>(featT, coord, cell,
                                            W0t, W1t, W2t, W3t, W4t,
                                            b0, b1, b2, b3, b4, preds);

    combine_kernel<<<(BQ * NOUT + 255) / 256, 256, 0, stream>>>(preds, out);
}

// Round 9
// 365.372 us; speedup vs baseline: 1.7160x; 1.7160x over previous
//
#include <hip/hip_runtime.h>
#include <hip/hip_bf16.h>

typedef _Float16 f16x8 __attribute__((ext_vector_type(8)));
typedef float f32x4 __attribute__((ext_vector_type(4)));

#define BQ 65536            // B*Q = 8*8192
#define KPAD0 640           // W0t row stride; effective K = 608 (last 32 all-pad skipped)
#define HID 256
#define NOUT 27
#define ZOFF 1179648        // featT element count; featT+ZOFF == zbuf (zeros)

// s_waitcnt vmcnt(n) only (expcnt=7, lgkmcnt=15 -> no wait on those)
#define WAITVM(n) __builtin_amdgcn_s_waitcnt(0x0F70 | (n))

// async global->LDS 16B: lane's data lands at (wave-uniform base) + lane*16
__device__ __forceinline__ void gl_lds16(const _Float16* g, _Float16* l) {
    __builtin_amdgcn_global_load_lds(
        (const __attribute__((address_space(1))) void*)g,
        (__attribute__((address_space(3))) void*)l, 16, 0, 0);
}

// ---------------- feat (B,C,H,W) f32 -> featT (B,H,W,C) f16 -----------------
__global__ __launch_bounds__(256) void feat_transpose(
    const float* __restrict__ feat, _Float16* __restrict__ featT,
    _Float16* __restrict__ zbuf)
{
    __shared__ float tile[64 * 49];
    int bh = blockIdx.x;                 // 0..383 = b*48+h
    int b = bh / 48, h = bh - b * 48;
    int t = threadIdx.x;
    if (bh == 0 && t < 128) zbuf[t] = (_Float16)0.f;
    #pragma unroll
    for (int i = 0; i < 12; i++) {
        int idx = t + i * 256;           // < 3072
        int c = idx / 48, w = idx - c * 48;
        tile[c * 49 + w] = feat[(((size_t)b * 64 + c) * 48 + h) * 48 + w];
    }
    __syncthreads();
    #pragma unroll
    for (int i = 0; i < 12; i++) {
        int idx = t + i * 256;
        int w = idx >> 6, c = idx & 63;
        featT[(((size_t)b * 48 + h) * 48 + w) * 64 + c] = (_Float16)tile[c * 49 + w];
    }
}

// ---------------- weight transpose+cast: wt[n*Kpad+k] = w[k*Nin+n] ----------
__global__ void transpose_cast(const float* __restrict__ w, _Float16* __restrict__ wt,
                               int Kin, int Nin, int Kpad, int Npad) {
    int idx = blockIdx.x * 256 + threadIdx.x;
    if (idx >= Npad * Kpad) return;
    int n = idx / Kpad, k = idx - n * Kpad;
    float v = (n < Nin && k < Kin) ? w[k * Nin + n] : 0.f;
    wt[idx] = (_Float16)v;
}

// w0 with K-permutation: kp<576 -> src_k = (kp&63)*9 + (kp>>6)  (pixel-major)
__global__ void transpose_cast_w0(const float* __restrict__ w0, _Float16* __restrict__ wt) {
    int idx = blockIdx.x * 256 + threadIdx.x;
    if (idx >= 256 * KPAD0) return;
    int n = idx / KPAD0, kp = idx - n * KPAD0;
    int src = (kp < 576) ? ((kp & 63) * 9 + (kp >> 6)) : kp;
    float v = (src < 596) ? w0[src * 256 + n] : 0.f;
    wt[idx] = (_Float16)v;
}

// ---------------- megakernel: one (64-row, shift) tile, 5 layers ------------
// grid = 4096: s = blk&3, bq0 = (blk>>2)*64. 256 thr = 4 waves (N-split).
// K-loops are BARRIER-FREE with wave-private double-buffered LDS staging:
// each wave DMAs (global_load_lds) only the operand rows IT consumes, so the
// DMA->ds_read dependency is wave-local; explicit s_waitcnt vmcnt(N) with
// one-step prefetch hides L2 latency (vmcnt retires oldest-first, m135).
// Barriers (~10/block) only at layer boundaries, at drained points.
__global__ __launch_bounds__(256, 2) void mega(
    const _Float16* __restrict__ featT, const float* __restrict__ coord,
    const float* __restrict__ cell,
    const _Float16* __restrict__ W0t, const _Float16* __restrict__ W1t,
    const _Float16* __restrict__ W2t, const _Float16* __restrict__ W3t,
    const _Float16* __restrict__ W4t,
    const float* __restrict__ b0, const float* __restrict__ b1,
    const float* __restrict__ b2, const float* __restrict__ b3,
    const float* __restrict__ b4, float* __restrict__ preds)
{
    __shared__ _Float16 act[64 * 256];     // 32 KB; during L0: per-wave A dbuf
    __shared__ _Float16 Bsw[4][2][2048];   // 32 KB per-wave B dbuf (4 KB each)
    __shared__ int   rc_s[64][2];
    __shared__ float q_s[64][2];
    __shared__ float wgt[64];

    int t = threadIdx.x;
    int wave = t >> 6, lane = t & 63;
    int lrow = lane & 15, lq = lane >> 4;
    int blk = blockIdx.x;
    int s = blk & 3;
    int bq0 = (blk >> 2) * 64;

    // ---- prologue: this shift's rc/q + all-4 areas -> blend weight ----------
    if (t < 64) {
        int bq = bq0 + t;
        const float* cp = coord + (size_t)bq * 18;
        float areas[4]; int mri = 0, mci = 0; float mqx = 0.f, mqy = 0.f;
        #pragma unroll
        for (int ss = 0; ss < 4; ss++) {
            float vx = (ss & 2) ? 1.f : -1.f, vy = (ss & 1) ? 1.f : -1.f;
            float cx = cp[8] + vx * (1.f / 48.f) + 1e-6f;
            float cy = cp[9] + vy * (1.f / 48.f) + 1e-6f;
            cx = fminf(fmaxf(cx, -1.f + 1e-6f), 1.f - 1e-6f);
            cy = fminf(fmaxf(cy, -1.f + 1e-6f), 1.f - 1e-6f);
            int ri = (int)rintf((cx + 1.f) * 24.f - 0.5f); ri = min(max(ri, 0), 47);
            int ci = (int)rintf((cy + 1.f) * 24.f - 0.5f); ci = min(max(ci, 0), 47);
            float qx = (float)(2 * ri + 1) / 48.f - 1.f;
            float qy = (float)(2 * ci + 1) / 48.f - 1.f;
            areas[ss] = fabsf((cp[0] - qx) * 2304.f * (cp[1] - qy)) + 1e-9f;
            if (ss == s) { mri = ri; mci = ci; mqx = qx; mqy = qy; }
        }
        float tot = areas[0] + areas[1] + areas[2] + areas[3];
        wgt[t] = areas[s ^ 3] / tot;
        rc_s[t][0] = mri; rc_s[t][1] = mci;
        q_s[t][0] = mqx;  q_s[t][1] = mqy;
    }
    __syncthreads();

    int gdat = (lane & 3) ^ ((lane >> 3) & 3);   // swizzled source 8-f16 group
    int rsl  = lane >> 2;                        // row-in-slab 0..15

    // per-lane A-source constants for the 4 rows this lane stages
    int rA[4], cA[4], bA[4];
    #pragma unroll
    for (int j = 0; j < 4; j++) {
        int arow = j * 16 + rsl;
        rA[j] = rc_s[arow][0];
        cA[j] = rc_s[arow][1];
        bA[j] = ((bq0 + arow) >> 13) * 147456;   // b * 48*48*64
    }

    f32x4 acc[4][4];
    #pragma unroll
    for (int mi = 0; mi < 4; mi++)
        #pragma unroll
        for (int ni = 0; ni < 4; ni++) acc[mi][ni] = (f32x4){0.f, 0.f, 0.f, 0.f};

    // ================= layer 0: 18 pipelined K-steps of 32 ===================
    {
        auto stageL0 = [&](int step, int buf) {
            int p = step >> 1, half = step & 1;
            int di = p / 3 - 1, dj = p - (p / 3) * 3 - 1;
            int k0 = p * 64 + half * 32;
            #pragma unroll
            for (int j = 0; j < 4; j++) {
                int r2 = rA[j] + di, c2 = cA[j] + dj;
                int off = ((unsigned)r2 < 48u && (unsigned)c2 < 48u)
                        ? bA[j] + ((r2 * 48 + c2) << 6) : ZOFF;
                gl_lds16(featT + off + half * 32 + gdat * 8,
                         act + wave * 4096 + buf * 2048 + j * 512);
                gl_lds16(W0t + (size_t)(wave * 64 + j * 16 + rsl) * KPAD0 + k0 + gdat * 8,
                         &Bsw[wave][buf][j * 512]);
            }
        };
        stageL0(0, 0);
        #pragma unroll
        for (int step = 0; step < 18; step++) {
            if (step < 17) { stageL0(step + 1, (step + 1) & 1); WAITVM(8); }
            else           { WAITVM(0); }
            const _Float16* Ab = act + wave * 4096 + (step & 1) * 2048;
            const _Float16* Bb = &Bsw[wave][step & 1][0];
            f16x8 af[4], bf[4];
            #pragma unroll
            for (int mi = 0; mi < 4; mi++) {
                int row = mi * 16 + lrow;
                af[mi] = *(const f16x8*)&Ab[row * 32 + ((lq ^ ((row >> 1) & 3)) << 3)];
            }
            #pragma unroll
            for (int ni = 0; ni < 4; ni++) {
                int row = ni * 16 + lrow;
                bf[ni] = *(const f16x8*)&Bb[row * 32 + ((lq ^ ((row >> 1) & 3)) << 3)];
            }
            #pragma unroll
            for (int mi = 0; mi < 4; mi++)
                #pragma unroll
                for (int ni = 0; ni < 4; ni++)
                    acc[mi][ni] = __builtin_amdgcn_mfma_f32_16x16x32_f16(
                        af[mi], bf[ni], acc[mi][ni], 0, 0, 0);
        }
    }
    {   // rel/cell chunk (k = 576..607): operands in registers (pipeline drained)
        f16x8 af[4], bf[4];
        #pragma unroll
        for (int mi = 0; mi < 4; mi++) {
            int row = mi * 16 + lrow;
            int bq = bq0 + row;
            const float* cp2 = coord + (size_t)bq * 18;
            float qx = q_s[row][0], qy = q_s[row][1];
            _Float16 tmp[8];
            #pragma unroll
            for (int j = 0; j < 8; j++) {
                int idx = lq * 8 + j;
                float v;
                if (idx < 18) v = (idx & 1) ? (cp2[idx] - qy) : ((cp2[idx] - qx) * 2304.f);
                else if (idx == 18) v = cell[(size_t)bq * 2] * 48.f;
                else if (idx == 19) v = cell[(size_t)bq * 2 + 1] * 48.f;
                else v = 0.f;
                tmp[j] = (_Float16)v;
            }
            af[mi] = *(f16x8*)tmp;
        }
        #pragma unroll
        for (int ni = 0; ni < 4; ni++) {
            int br = wave * 64 + ni * 16 + lrow;
            bf[ni] = *(const f16x8*)&W0t[(size_t)br * KPAD0 + 576 + lq * 8];
        }
        #pragma unroll
        for (int mi = 0; mi < 4; mi++)
            #pragma unroll
            for (int ni = 0; ni < 4; ni++)
                acc[mi][ni] = __builtin_amdgcn_mfma_f32_16x16x32_f16(
                    af[mi], bf[ni], acc[mi][ni], 0, 0, 0);
    }
    __syncthreads();   // other waves may still read their A-dbuf inside act
    {   // act = relu(acc + b0)
        float bvv[4];
        #pragma unroll
        for (int ni = 0; ni < 4; ni++) bvv[ni] = b0[wave * 64 + ni * 16 + lrow];
        #pragma unroll
        for (int mi = 0; mi < 4; mi++)
            #pragma unroll
            for (int ni = 0; ni < 4; ni++) {
                int cw = wave * 64 + ni * 16 + lrow;
                #pragma unroll
                for (int rr = 0; rr < 4; rr++) {
                    float v = acc[mi][ni][rr] + bvv[ni];
                    v = v > 0.f ? v : 0.f;
                    int rw = mi * 16 + lq * 4 + rr;
                    int gp = ((cw >> 3) ^ (rw & 31)) & 31;
                    act[rw * 256 + gp * 8 + (cw & 7)] = (_Float16)v;
                }
            }
    }
    __syncthreads();

    // ================= hidden layers 1..3: pipelined, barrier-free ===========
    for (int layer = 0; layer < 3; layer++) {
        const _Float16* Wl = (layer == 0) ? W1t : (layer == 1) ? W2t : W3t;
        const float*    bl = (layer == 0) ? b1  : (layer == 1) ? b2  : b3;
        auto stageH = [&](int k, int buf) {
            #pragma unroll
            for (int j = 0; j < 4; j++)
                gl_lds16(Wl + (size_t)(wave * 64 + j * 16 + rsl) * 256 + k * 32 + gdat * 8,
                         &Bsw[wave][buf][j * 512]);
        };
        #pragma unroll
        for (int mi = 0; mi < 4; mi++)
            #pragma unroll
            for (int ni = 0; ni < 4; ni++) acc[mi][ni] = (f32x4){0.f, 0.f, 0.f, 0.f};
        stageH(0, 0);
        #pragma unroll
        for (int k = 0; k < 8; k++) {
            if (k < 7) { stageH(k + 1, (k + 1) & 1); WAITVM(4); }
            else       { WAITVM(0); }
            const _Float16* Bb = &Bsw[wave][k & 1][0];
            f16x8 af[4], bf[4];
            #pragma unroll
            for (int mi = 0; mi < 4; mi++) {
                int ar = mi * 16 + lrow;
                int gp = (((k * 4) + lq) ^ (ar & 31)) & 31;
                af[mi] = *(const f16x8*)&act[ar * 256 + gp * 8];
            }
            #pragma unroll
            for (int ni = 0; ni < 4; ni++) {
                int row = ni * 16 + lrow;
                bf[ni] = *(const f16x8*)&Bb[row * 32 + ((lq ^ ((row >> 1) & 3)) << 3)];
            }
            #pragma unroll
            for (int mi = 0; mi < 4; mi++)
                #pragma unroll
                for (int ni = 0; ni < 4; ni++)
                    acc[mi][ni] = __builtin_amdgcn_mfma_f32_16x16x32_f16(
                        af[mi], bf[ni], acc[mi][ni], 0, 0, 0);
        }
        __syncthreads();   // all act reads done before in-place overwrite
        {
            float bvv[4];
            #pragma unroll
            for (int ni = 0; ni < 4; ni++) bvv[ni] = bl[wave * 64 + ni * 16 + lrow];
            #pragma unroll
            for (int mi = 0; mi < 4; mi++)
                #pragma unroll
                for (int ni = 0; ni < 4; ni++) {
                    int cw = wave * 64 + ni * 16 + lrow;
                    #pragma unroll
                    for (int rr = 0; rr < 4; rr++) {
                        float v = acc[mi][ni][rr] + bvv[ni];
                        v = v > 0.f ? v : 0.f;
                        int rw = mi * 16 + lq * 4 + rr;
                        int gp = ((cw >> 3) ^ (rw & 31)) & 31;
                        act[rw * 256 + gp * 8 + (cw & 7)] = (_Float16)v;
                    }
                }
        }
        __syncthreads();
    }

    // ================= final layer: M-split waves, pipelined =================
    f32x4 acc2[2];
    acc2[0] = (f32x4){0.f, 0.f, 0.f, 0.f};
    acc2[1] = (f32x4){0.f, 0.f, 0.f, 0.f};
    int mrow0 = wave * 16;
    {
        auto stage4 = [&](int k, int buf) {
            #pragma unroll
            for (int j = 0; j < 2; j++)
                gl_lds16(W4t + (size_t)(j * 16 + rsl) * 256 + k * 32 + gdat * 8,
                         &Bsw[wave][buf][j * 512]);
        };
        stage4(0, 0);
        #pragma unroll
        for (int k = 0; k < 8; k++) {
            if (k < 7) { stage4(k + 1, (k + 1) & 1); WAITVM(2); }
            else       { WAITVM(0); }
            const _Float16* Bb = &Bsw[wave][k & 1][0];
            f16x8 af, bf[2];
            {
                int ar = mrow0 + lrow;
                int gp = (((k * 4) + lq) ^ (ar & 31)) & 31;
                af = *(const f16x8*)&act[ar * 256 + gp * 8];
            }
            #pragma unroll
            for (int ni = 0; ni < 2; ni++) {
                int row = ni * 16 + lrow;
                bf[ni] = *(const f16x8*)&Bb[row * 32 + ((lq ^ ((row >> 1) & 3)) << 3)];
            }
            #pragma unroll
            for (int ni = 0; ni < 2; ni++)
                acc2[ni] = __builtin_amdgcn_mfma_f32_16x16x32_f16(af, bf[ni], acc2[ni], 0, 0, 0);
        }
    }

    // weighted partial -> exclusive preds[s] slice (plain stores, no atomics)
    {
        float bv0 = b4[lrow];
        float bv1 = (lrow < 11) ? b4[16 + lrow] : 0.f;
        float* pr = preds + (size_t)s * (BQ * NOUT);
        #pragma unroll
        for (int rr = 0; rr < 4; rr++) {
            int row = mrow0 + lq * 4 + rr;
            float w = wgt[row];
            size_t obase = (size_t)(bq0 + row) * 27;
            pr[obase + lrow] = w * (acc2[0][rr] + bv0);
            if (lrow < 11)
                pr[obase + 16 + lrow] = w * (acc2[1][rr] + bv1);
        }
    }
}

// ---------------- combine: out = sum of 4 weighted partials ------------------
__global__ __launch_bounds__(256) void combine_kernel(
    const float* __restrict__ preds, float* __restrict__ out)
{
    int idx = blockIdx.x * 256 + threadIdx.x;
    if (idx >= BQ * NOUT) return;
    const size_t st = (size_t)BQ * NOUT;
    out[idx] = preds[idx] + preds[st + idx] + preds[2 * st + idx] + preds[3 * st + idx];
}

extern "C" void kernel_launch(void* const* d_in, const int* in_sizes, int n_in,
                              void* d_out, int out_size, void* d_ws, size_t ws_size,
                              hipStream_t stream) {
    const float* feat  = (const float*)d_in[0];
    const float* coord = (const float*)d_in[1];
    const float* cell  = (const float*)d_in[2];
    const float* w0 = (const float*)d_in[3];  const float* b0 = (const float*)d_in[4];
    const float* w1 = (const float*)d_in[5];  const float* b1 = (const float*)d_in[6];
    const float* w2 = (const float*)d_in[7];  const float* b2 = (const float*)d_in[8];
    const float* w3 = (const float*)d_in[9];  const float* b3 = (const float*)d_in[10];
    const float* w4 = (const float*)d_in[11]; const float* b4 = (const float*)d_in[12];
    float* out = (float*)d_out;

    char* ws = (char*)d_ws;
    size_t off = 0;
    _Float16* W0t = (_Float16*)(ws + off); off += (size_t)256 * KPAD0 * 2;
    _Float16* W1t = (_Float16*)(ws + off); off += (size_t)256 * 256 * 2;
    _Float16* W2t = (_Float16*)(ws + off); off += (size_t)256 * 256 * 2;
    _Float16* W3t = (_Float16*)(ws + off); off += (size_t)256 * 256 * 2;
    _Float16* W4t = (_Float16*)(ws + off); off += (size_t)32 * 256 * 2;
    _Float16* featT = (_Float16*)(ws + off); off += (size_t)ZOFF * 2;
    _Float16* zbuf  = (_Float16*)(ws + off); off += 512;   // featT + ZOFF == zbuf
    float* preds    = (float*)(ws + off);    off += (size_t)4 * BQ * NOUT * 4;

    feat_transpose<<<8 * 48, 256, 0, stream>>>(feat, featT, zbuf);
    transpose_cast_w0<<<(256 * KPAD0 + 255) / 256, 256, 0, stream>>>(w0, W0t);
    transpose_cast<<<256, 256, 0, stream>>>(w1, W1t, 256, 256, 256, 256);
    transpose_cast<<<256, 256, 0, stream>>>(w2, W2t, 256, 256, 256, 256);
    transpose_cast<<<256, 256, 0, stream>>>(w3, W3t, 256, 256, 256, 256);
    transpose_cast<<<32, 256, 0, stream>>>(w4, W4t, 256, NOUT, 256, 32);

    mega<<<4 * (BQ / 64), 256, 0, stream>>>(featT, coord, cell,
                                            W0t, W1t, W2t, W3t, W4t,
                                            b0, b1, b2, b3, b4, preds);

    combine_kernel<<<(BQ * NOUT + 255) / 256, 256, 0, stream>>>(preds, out);
}